// Round 1
// baseline (2515.996 us; speedup 1.0000x reference)
//
#include <hip/hip_runtime.h>

#define N_ENT 50000
#define N_REL 500
#define N_EDGE 500000
#define HEADS 2
#define DIM 64
#define POW_ITER 3
#define ALPHA 0.15f
#define LN_EPS 1e-5f

// ---- float <-> order-preserving uint encoding (for atomicMax on floats) ----
static __device__ __forceinline__ unsigned enc_f(float f) {
  unsigned u = __float_as_uint(f);
  return (u >> 31) ? ~u : (u | 0x80000000u);
}
static __device__ __forceinline__ float dec_f(unsigned u) {
  return (u >> 31) ? __uint_as_float(u & 0x7fffffffu) : __uint_as_float(~u);
}

// ---- LayerNorm: one wave (64 lanes) per node ----
__global__ void ln_kernel(const float* __restrict__ x, const float* __restrict__ g,
                          const float* __restrict__ b, float* __restrict__ h) {
  int wid = (blockIdx.x * blockDim.x + threadIdx.x) >> 6;
  int lane = threadIdx.x & 63;
  if (wid >= N_ENT) return;
  float v = x[wid * 64 + lane];
  float s = v;
#pragma unroll
  for (int off = 32; off; off >>= 1) s += __shfl_xor(s, off);
  float mu = s * (1.0f / 64.0f);
  float d = v - mu;
  float s2 = d * d;
#pragma unroll
  for (int off = 32; off; off >>= 1) s2 += __shfl_xor(s2, off);
  float rs = rsqrtf(s2 * (1.0f / 64.0f) + LN_EPS);
  h[wid * 64 + lane] = d * rs * g[lane] + b[lane];
}

// ---- node scores: s[m, head] = sum_d tanh((x @ W)[m, head*64+d]) * att[head, d] ----
// one wave per node; W (64x128) + att staged in LDS
__global__ void scores_kernel(const float* __restrict__ x, const float* __restrict__ W,
                              const float* __restrict__ att, float* __restrict__ s_out,
                              int M) {
  __shared__ float Ws[64][128];
  __shared__ float atts[2][64];
  for (int i = threadIdx.x; i < 64 * 128; i += blockDim.x) Ws[i >> 7][i & 127] = W[i];
  for (int i = threadIdx.x; i < 128; i += blockDim.x) atts[i >> 6][i & 63] = att[i];
  __syncthreads();
  int lane = threadIdx.x & 63;
  int wpb = blockDim.x >> 6;
  int n = blockIdx.x * wpb + (threadIdx.x >> 6);
  if (n >= M) return;
  float hv = x[n * 64 + lane];
  float acc0 = 0.f, acc1 = 0.f;
#pragma unroll
  for (int d = 0; d < 64; ++d) {
    float bv = __shfl(hv, d);
    acc0 += bv * Ws[d][lane];
    acc1 += bv * Ws[d][lane + 64];
  }
  float t0 = tanhf(acc0) * atts[0][lane];
  float t1 = tanhf(acc1) * atts[1][lane];
#pragma unroll
  for (int off = 32; off; off >>= 1) {
    t0 += __shfl_xor(t0, off);
    t1 += __shfl_xor(t1, off);
  }
  if (lane == 0) {
    s_out[n * 2 + 0] = t0;
    s_out[n * 2 + 1] = t1;
  }
}

// ---- edge score + segment max (by src) ----
__global__ void edge_score_kernel(const int* __restrict__ src, const int* __restrict__ dst,
                                  const int* __restrict__ et, const float* __restrict__ s_h,
                                  const float* __restrict__ s_t, const float* __restrict__ s_r,
                                  float* __restrict__ A, unsigned* __restrict__ m_enc) {
  int i = blockIdx.x * blockDim.x + threadIdx.x;
  if (i >= N_EDGE * HEADS) return;
  int e = i >> 1, hh = i & 1;
  int s = src[e], d = dst[e], r = et[e];
  float sc = s_h[s * 2 + hh] + s_t[d * 2 + hh] + s_r[r * 2 + hh];
  sc = (sc >= 0.f) ? sc : 0.01f * sc;  // leaky_relu, slope 0.01
  A[i] = sc;
  atomicMax(&m_enc[s * 2 + hh], enc_f(sc));
}

// ---- exp(score - max) + segment sum ----
__global__ void edge_exp_kernel(const int* __restrict__ src, float* __restrict__ A,
                                const unsigned* __restrict__ m_enc, float* __restrict__ z) {
  int i = blockIdx.x * blockDim.x + threadIdx.x;
  if (i >= N_EDGE * HEADS) return;
  int e = i >> 1, hh = i & 1;
  int s = src[e];
  float w = expf(A[i] - dec_f(m_enc[s * 2 + hh]));
  A[i] = w;
  atomicAdd(&z[s * 2 + hh], w);
}

// ---- normalize: A = (1-alpha) * w / z[src] ----
__global__ void edge_norm_kernel(const int* __restrict__ src, float* __restrict__ A,
                                 const float* __restrict__ z) {
  int i = blockIdx.x * blockDim.x + threadIdx.x;
  if (i >= N_EDGE * HEADS) return;
  int e = i >> 1, hh = i & 1;
  A[i] = (1.0f - ALPHA) * A[i] / z[src[e] * 2 + hh];
}

// ---- Z init (scale * h broadcast over heads) ----
__global__ void initZ_kernel(const float* __restrict__ h, float* __restrict__ Z, float scale) {
  int i = blockIdx.x * blockDim.x + threadIdx.x;
  if (i >= N_ENT * 128) return;
  int n = i >> 7, d = i & 63;
  Z[i] = scale * h[n * 64 + d];
}

// ---- message passing: Znext[src] += A[e] * Z[dst], 128 threads per edge ----
__global__ void edge_msg_kernel(const int* __restrict__ src, const int* __restrict__ dst,
                                const float* __restrict__ A, const float* __restrict__ Z,
                                float* __restrict__ Zn) {
  int i = blockIdx.x * blockDim.x + threadIdx.x;
  if (i >= N_EDGE * 128) return;
  int e = i >> 7;
  int t = i & 127;
  int hh = t >> 6;
  float a = A[e * 2 + hh];
  float v = a * Z[dst[e] * 128 + t];
  atomicAdd(&Zn[src[e] * 128 + t], v);
}

// ---- output: out = Z.reshape(N,128) @ W_o + x ; one wave per node ----
__global__ void out_kernel(const float* __restrict__ Z, const float* __restrict__ Wo,
                           const float* __restrict__ x, float* __restrict__ out) {
  __shared__ float Wos[128][64];
  for (int i = threadIdx.x; i < 128 * 64; i += blockDim.x) Wos[i >> 6][i & 63] = Wo[i];
  __syncthreads();
  int lane = threadIdx.x & 63;
  int wpb = blockDim.x >> 6;
  int n = blockIdx.x * wpb + (threadIdx.x >> 6);
  if (n >= N_ENT) return;
  float zlo = Z[n * 128 + lane];
  float zhi = Z[n * 128 + 64 + lane];
  float acc = 0.f;
#pragma unroll
  for (int c = 0; c < 64; ++c) {
    acc += __shfl(zlo, c) * Wos[c][lane];
    acc += __shfl(zhi, c) * Wos[64 + c][lane];
  }
  out[n * 64 + lane] = acc + x[n * 64 + lane];
}

extern "C" void kernel_launch(void* const* d_in, const int* in_sizes, int n_in,
                              void* d_out, int out_size, void* d_ws, size_t ws_size,
                              hipStream_t stream) {
  const float* ent0 = (const float*)d_in[0];
  const float* rel  = (const float*)d_in[1];
  const int* eidx   = (const int*)d_in[2];
  const int* src    = eidx;
  const int* dst    = eidx + N_EDGE;
  const int* et     = (const int*)d_in[3];
  const float* gam  = (const float*)d_in[4];
  const float* bet  = (const float*)d_in[5];
  const float* W_h  = (const float*)d_in[6];
  const float* W_t  = (const float*)d_in[7];
  const float* W_r  = (const float*)d_in[8];
  const float* att_h = (const float*)d_in[9];
  const float* att_t = (const float*)d_in[10];
  const float* att_r = (const float*)d_in[11];
  const float* W_o  = (const float*)d_in[12];
  float* outp = (float*)d_out;

  char* w = (char*)d_ws;
  auto alloc = [&](size_t bytes) {
    char* p = w;
    w += (bytes + 255) & ~(size_t)255;
    return p;
  };
  float* ent1   = (float*)alloc((size_t)N_ENT * 64 * 4);
  float* h      = (float*)alloc((size_t)N_ENT * 64 * 4);
  float* s_h    = (float*)alloc((size_t)N_ENT * 2 * 4);
  float* s_t    = (float*)alloc((size_t)N_ENT * 2 * 4);
  float* s_r    = (float*)alloc((size_t)N_REL * 2 * 4);
  unsigned* m_e = (unsigned*)alloc((size_t)N_ENT * 2 * 4);
  float* z      = (float*)alloc((size_t)N_ENT * 2 * 4);
  float* A      = (float*)alloc((size_t)N_EDGE * 2 * 4);
  float* Z      = (float*)alloc((size_t)N_ENT * 128 * 4);
  float* Zn     = (float*)alloc((size_t)N_ENT * 128 * 4);

  const int EH = N_EDGE * HEADS;
  for (int l = 0; l < 2; ++l) {
    const float* x = (l == 0) ? ent0 : ent1;
    float* y = (l == 0) ? ent1 : outp;

    ln_kernel<<<(N_ENT + 3) / 4, 256, 0, stream>>>(x, gam + l * 64, bet + l * 64, h);
    scores_kernel<<<(N_ENT + 3) / 4, 256, 0, stream>>>(h, W_h + l * 8192, att_h + l * 128, s_h, N_ENT);
    scores_kernel<<<(N_ENT + 3) / 4, 256, 0, stream>>>(h, W_t + l * 8192, att_t + l * 128, s_t, N_ENT);
    scores_kernel<<<(N_REL + 3) / 4, 256, 0, stream>>>(rel, W_r + l * 8192, att_r + l * 128, s_r, N_REL);

    hipMemsetAsync(m_e, 0, (size_t)N_ENT * 2 * 4, stream);
    hipMemsetAsync(z, 0, (size_t)N_ENT * 2 * 4, stream);

    edge_score_kernel<<<(EH + 255) / 256, 256, 0, stream>>>(src, dst, et, s_h, s_t, s_r, A, m_e);
    edge_exp_kernel<<<(EH + 255) / 256, 256, 0, stream>>>(src, A, m_e, z);
    edge_norm_kernel<<<(EH + 255) / 256, 256, 0, stream>>>(src, A, z);

    initZ_kernel<<<(N_ENT * 128 + 255) / 256, 256, 0, stream>>>(h, Z, 1.0f);
    float* Zc = Z;
    float* Zx = Zn;
    for (int it = 0; it < POW_ITER; ++it) {
      initZ_kernel<<<(N_ENT * 128 + 255) / 256, 256, 0, stream>>>(h, Zx, ALPHA);
      edge_msg_kernel<<<(N_EDGE * 128 + 255) / 256, 256, 0, stream>>>(src, dst, A, Zc, Zx);
      float* tmp = Zc; Zc = Zx; Zx = tmp;
    }

    out_kernel<<<(N_ENT + 3) / 4, 256, 0, stream>>>(Zc, W_o + l * 8192, x, y);
  }
}

// Round 2
// 2032.800 us; speedup vs baseline: 1.2377x; 1.2377x over previous
//
#include <hip/hip_runtime.h>

#define N_ENT 50000
#define N_REL 500
#define N_EDGE 500000
#define HEADS 2
#define DIM 64
#define POW_ITER 3
#define ALPHA 0.15f
#define LN_EPS 1e-5f

// ---- float <-> order-preserving uint encoding (for atomicMax on floats) ----
static __device__ __forceinline__ unsigned enc_f(float f) {
  unsigned u = __float_as_uint(f);
  return (u >> 31) ? ~u : (u | 0x80000000u);
}
static __device__ __forceinline__ float dec_f(unsigned u) {
  return (u >> 31) ? __uint_as_float(u & 0x7fffffffu) : __uint_as_float(~u);
}

// ---- LayerNorm: one wave (64 lanes) per node ----
__global__ void ln_kernel(const float* __restrict__ x, const float* __restrict__ g,
                          const float* __restrict__ b, float* __restrict__ h) {
  int wid = (blockIdx.x * blockDim.x + threadIdx.x) >> 6;
  int lane = threadIdx.x & 63;
  if (wid >= N_ENT) return;
  float v = x[wid * 64 + lane];
  float s = v;
#pragma unroll
  for (int off = 32; off; off >>= 1) s += __shfl_xor(s, off);
  float mu = s * (1.0f / 64.0f);
  float d = v - mu;
  float s2 = d * d;
#pragma unroll
  for (int off = 32; off; off >>= 1) s2 += __shfl_xor(s2, off);
  float rs = rsqrtf(s2 * (1.0f / 64.0f) + LN_EPS);
  h[wid * 64 + lane] = d * rs * g[lane] + b[lane];
}

// ---- node scores: s[m, head] = sum_d tanh((x @ W)[m, head*64+d]) * att[head, d] ----
// one wave per node; W (64x128) + att staged in LDS; 1024 threads = 16 nodes/block
__global__ void scores_kernel(const float* __restrict__ x, const float* __restrict__ W,
                              const float* __restrict__ att, float* __restrict__ s_out,
                              int M) {
  __shared__ float Ws[64][128];
  __shared__ float atts[2][64];
  for (int i = threadIdx.x; i < 64 * 128; i += blockDim.x) Ws[i >> 7][i & 127] = W[i];
  for (int i = threadIdx.x; i < 128; i += blockDim.x) atts[i >> 6][i & 63] = att[i];
  __syncthreads();
  int lane = threadIdx.x & 63;
  int wpb = blockDim.x >> 6;
  int n = blockIdx.x * wpb + (threadIdx.x >> 6);
  if (n >= M) return;
  float hv = x[n * 64 + lane];
  float acc0 = 0.f, acc1 = 0.f;
#pragma unroll
  for (int d = 0; d < 64; ++d) {
    float bv = __shfl(hv, d);
    acc0 += bv * Ws[d][lane];
    acc1 += bv * Ws[d][lane + 64];
  }
  float t0 = tanhf(acc0) * atts[0][lane];
  float t1 = tanhf(acc1) * atts[1][lane];
#pragma unroll
  for (int off = 32; off; off >>= 1) {
    t0 += __shfl_xor(t0, off);
    t1 += __shfl_xor(t1, off);
  }
  if (lane == 0) {
    s_out[n * 2 + 0] = t0;
    s_out[n * 2 + 1] = t1;
  }
}

// ================= CSR build (once per launch) =================
__global__ void deg_kernel(const int* __restrict__ src, int* __restrict__ deg) {
  int e = blockIdx.x * blockDim.x + threadIdx.x;
  if (e >= N_EDGE) return;
  atomicAdd(&deg[src[e]], 1);
}

// single-block exclusive scan of deg[0..N_ENT) -> rowptr[0..N_ENT]
__global__ void scan_kernel(const int* __restrict__ deg, int* __restrict__ rowptr) {
  __shared__ int sums[1024];
  int t = threadIdx.x;
  const int C = (N_ENT + 1023) / 1024;  // 49
  int base = t * C;
  int s = 0;
  for (int i = 0; i < C; ++i) {
    int idx = base + i;
    if (idx < N_ENT) s += deg[idx];
  }
  sums[t] = s;
  __syncthreads();
  for (int off = 1; off < 1024; off <<= 1) {
    int v = (t >= off) ? sums[t - off] : 0;
    __syncthreads();
    sums[t] += v;
    __syncthreads();
  }
  int run = (t == 0) ? 0 : sums[t - 1];
  for (int i = 0; i < C; ++i) {
    int idx = base + i;
    if (idx <= N_ENT) rowptr[idx] = run;
    if (idx < N_ENT) run += deg[idx];
  }
}

__global__ void scatter_kernel(const int* __restrict__ src, int* __restrict__ cursor,
                               int* __restrict__ csr_eid) {
  int e = blockIdx.x * blockDim.x + threadIdx.x;
  if (e >= N_EDGE) return;
  int p = atomicAdd(&cursor[src[e]], 1);
  csr_eid[p] = e;
}

// ================= edge passes =================
// per-edge (both heads): score + segment max (by src)
__global__ void edge_score_kernel(const int* __restrict__ src, const int* __restrict__ dst,
                                  const int* __restrict__ et, const float* __restrict__ s_h,
                                  const float* __restrict__ s_t, const float* __restrict__ s_r,
                                  float* __restrict__ A, unsigned* __restrict__ m_enc) {
  int e = blockIdx.x * blockDim.x + threadIdx.x;
  if (e >= N_EDGE) return;
  int s = src[e], d = dst[e], r = et[e];
  const float2* sh2 = (const float2*)s_h;
  const float2* st2 = (const float2*)s_t;
  const float2* sr2 = (const float2*)s_r;
  float2 a = sh2[s], b = st2[d], c = sr2[r];
  float sc0 = a.x + b.x + c.x;
  float sc1 = a.y + b.y + c.y;
  sc0 = (sc0 >= 0.f) ? sc0 : 0.01f * sc0;
  sc1 = (sc1 >= 0.f) ? sc1 : 0.01f * sc1;
  ((float2*)A)[e] = make_float2(sc0, sc1);
  atomicMax(&m_enc[s * 2 + 0], enc_f(sc0));
  atomicMax(&m_enc[s * 2 + 1], enc_f(sc1));
}

// per-edge: w = exp(score - max), store raw w, accumulate z
__global__ void edge_exp_kernel(const int* __restrict__ src, float* __restrict__ A,
                                const unsigned* __restrict__ m_enc, float* __restrict__ z) {
  int e = blockIdx.x * blockDim.x + threadIdx.x;
  if (e >= N_EDGE) return;
  int s = src[e];
  float2 sc = ((float2*)A)[e];
  float w0 = expf(sc.x - dec_f(m_enc[s * 2 + 0]));
  float w1 = expf(sc.y - dec_f(m_enc[s * 2 + 1]));
  ((float2*)A)[e] = make_float2(w0, w1);
  atomicAdd(&z[s * 2 + 0], w0);
  atomicAdd(&z[s * 2 + 1], w1);
}

// ================= CSR SpMM (gather, no atomics) =================
// 128 threads per node: Zout[n,t] = alpha*h[n,t&63] + ((1-alpha)/z[n,hh]) * sum_e w_e * Zin[dst_e, t]
__global__ void spmm_kernel(const int* __restrict__ rowptr, const int* __restrict__ csr_eid,
                            const int* __restrict__ dst, const float* __restrict__ A,
                            const float* __restrict__ z, const float* __restrict__ h,
                            const float* __restrict__ Zin, float* __restrict__ Zout,
                            int zin_is_h) {
  int node = blockIdx.x * (blockDim.x >> 7) + (threadIdx.x >> 7);
  if (node >= N_ENT) return;
  int t = threadIdx.x & 127;
  int hh = t >> 6, dd = t & 63;
  int p0 = rowptr[node], p1 = rowptr[node + 1];
  float acc = 0.f;
  for (int p = p0; p < p1; ++p) {
    int e = csr_eid[p];
    int d = dst[e];
    float a = A[e * 2 + hh];
    float zv = zin_is_h ? h[d * 64 + dd] : Zin[d * 128 + t];
    acc += a * zv;
  }
  float c = (p1 > p0) ? (1.0f - ALPHA) / z[node * 2 + hh] : 0.f;
  Zout[node * 128 + t] = acc * c + ALPHA * h[node * 64 + dd];
}

// ---- output: out = Z.reshape(N,128) @ W_o + x ; one wave per node ----
__global__ void out_kernel(const float* __restrict__ Z, const float* __restrict__ Wo,
                           const float* __restrict__ x, float* __restrict__ out) {
  __shared__ float Wos[128][64];
  for (int i = threadIdx.x; i < 128 * 64; i += blockDim.x) Wos[i >> 6][i & 63] = Wo[i];
  __syncthreads();
  int lane = threadIdx.x & 63;
  int wpb = blockDim.x >> 6;
  int n = blockIdx.x * wpb + (threadIdx.x >> 6);
  if (n >= N_ENT) return;
  float zlo = Z[n * 128 + lane];
  float zhi = Z[n * 128 + 64 + lane];
  float acc = 0.f;
#pragma unroll
  for (int c = 0; c < 64; ++c) {
    acc += __shfl(zlo, c) * Wos[c][lane];
    acc += __shfl(zhi, c) * Wos[64 + c][lane];
  }
  out[n * 64 + lane] = acc + x[n * 64 + lane];
}

extern "C" void kernel_launch(void* const* d_in, const int* in_sizes, int n_in,
                              void* d_out, int out_size, void* d_ws, size_t ws_size,
                              hipStream_t stream) {
  const float* ent0 = (const float*)d_in[0];
  const float* rel  = (const float*)d_in[1];
  const int* eidx   = (const int*)d_in[2];
  const int* src    = eidx;
  const int* dst    = eidx + N_EDGE;
  const int* et     = (const int*)d_in[3];
  const float* gam  = (const float*)d_in[4];
  const float* bet  = (const float*)d_in[5];
  const float* W_h  = (const float*)d_in[6];
  const float* W_t  = (const float*)d_in[7];
  const float* W_r  = (const float*)d_in[8];
  const float* att_h = (const float*)d_in[9];
  const float* att_t = (const float*)d_in[10];
  const float* att_r = (const float*)d_in[11];
  const float* W_o  = (const float*)d_in[12];
  float* outp = (float*)d_out;

  char* w = (char*)d_ws;
  auto alloc = [&](size_t bytes) {
    char* p = w;
    w += (bytes + 255) & ~(size_t)255;
    return p;
  };
  float* ent1    = (float*)alloc((size_t)N_ENT * 64 * 4);
  float* h       = (float*)alloc((size_t)N_ENT * 64 * 4);
  float* s_h     = (float*)alloc((size_t)N_ENT * 2 * 4);
  float* s_t     = (float*)alloc((size_t)N_ENT * 2 * 4);
  float* s_r     = (float*)alloc((size_t)N_REL * 2 * 4);
  unsigned* m_e  = (unsigned*)alloc((size_t)N_ENT * 2 * 4);
  float* z       = (float*)alloc((size_t)N_ENT * 2 * 4);
  float* A       = (float*)alloc((size_t)N_EDGE * 2 * 4);
  float* Zb0     = (float*)alloc((size_t)N_ENT * 128 * 4);
  float* Zb1     = (float*)alloc((size_t)N_ENT * 128 * 4);
  int* deg       = (int*)alloc((size_t)N_ENT * 4);
  int* rowptr    = (int*)alloc((size_t)(N_ENT + 1) * 4);
  int* cursor    = (int*)alloc((size_t)N_ENT * 4);
  int* csr_eid   = (int*)alloc((size_t)N_EDGE * 4);

  const int EB = (N_EDGE + 255) / 256;

  // ---- CSR build (graph is layer-invariant) ----
  hipMemsetAsync(deg, 0, (size_t)N_ENT * 4, stream);
  deg_kernel<<<EB, 256, 0, stream>>>(src, deg);
  scan_kernel<<<1, 1024, 0, stream>>>(deg, rowptr);
  hipMemcpyAsync(cursor, rowptr, (size_t)N_ENT * 4, hipMemcpyDeviceToDevice, stream);
  scatter_kernel<<<EB, 256, 0, stream>>>(src, cursor, csr_eid);

  for (int l = 0; l < 2; ++l) {
    const float* x = (l == 0) ? ent0 : ent1;
    float* y = (l == 0) ? ent1 : outp;

    ln_kernel<<<(N_ENT + 3) / 4, 256, 0, stream>>>(x, gam + l * 64, bet + l * 64, h);
    scores_kernel<<<(N_ENT + 15) / 16, 1024, 0, stream>>>(h, W_h + l * 8192, att_h + l * 128, s_h, N_ENT);
    scores_kernel<<<(N_ENT + 15) / 16, 1024, 0, stream>>>(h, W_t + l * 8192, att_t + l * 128, s_t, N_ENT);
    scores_kernel<<<(N_REL + 15) / 16, 1024, 0, stream>>>(rel, W_r + l * 8192, att_r + l * 128, s_r, N_REL);

    hipMemsetAsync(m_e, 0, (size_t)N_ENT * 2 * 4, stream);
    hipMemsetAsync(z, 0, (size_t)N_ENT * 2 * 4, stream);

    edge_score_kernel<<<EB, 256, 0, stream>>>(src, dst, et, s_h, s_t, s_r, A, m_e);
    edge_exp_kernel<<<EB, 256, 0, stream>>>(src, A, m_e, z);

    // ---- PPR power iteration: 3 gather-SpMM, initZ + norm fused ----
    // it0: Zin = h (broadcast heads) -> Zb0 ; it1: Zb0 -> Zb1 ; it2: Zb1 -> Zb0
    spmm_kernel<<<(N_ENT + 1) / 2, 256, 0, stream>>>(rowptr, csr_eid, dst, A, z, h, h, Zb0, 1);
    spmm_kernel<<<(N_ENT + 1) / 2, 256, 0, stream>>>(rowptr, csr_eid, dst, A, z, h, Zb0, Zb1, 0);
    spmm_kernel<<<(N_ENT + 1) / 2, 256, 0, stream>>>(rowptr, csr_eid, dst, A, z, h, Zb1, Zb0, 0);

    out_kernel<<<(N_ENT + 15) / 16, 1024, 0, stream>>>(Zb0, W_o + l * 8192, x, y);
  }
}

// Round 3
// 1108.601 us; speedup vs baseline: 2.2695x; 1.8337x over previous
//
#include <hip/hip_runtime.h>

#define N_ENT 50000
#define N_REL 500
#define N_EDGE 500000
#define HEADS 2
#define DIM 64
#define POW_ITER 3
#define ALPHA 0.15f
#define LN_EPS 1e-5f

// ================= CSR build (once per launch; graph is layer-invariant) =================
__global__ void deg_kernel(const int* __restrict__ src, int* __restrict__ deg) {
  int e = blockIdx.x * blockDim.x + threadIdx.x;
  if (e >= N_EDGE) return;
  atomicAdd(&deg[src[e]], 1);
}

// single-block exclusive scan of deg[0..N_ENT) -> rowptr[0..N_ENT]
__global__ void scan_kernel(const int* __restrict__ deg, int* __restrict__ rowptr) {
  __shared__ int sums[1024];
  int t = threadIdx.x;
  const int C = (N_ENT + 1023) / 1024;  // 49
  int base = t * C;
  int s = 0;
  for (int i = 0; i < C; ++i) {
    int idx = base + i;
    if (idx < N_ENT) s += deg[idx];
  }
  sums[t] = s;
  __syncthreads();
  for (int off = 1; off < 1024; off <<= 1) {
    int v = (t >= off) ? sums[t - off] : 0;
    __syncthreads();
    sums[t] += v;
    __syncthreads();
  }
  int run = (t == 0) ? 0 : sums[t - 1];
  for (int i = 0; i < C; ++i) {
    int idx = base + i;
    if (idx <= N_ENT) rowptr[idx] = run;
    if (idx < N_ENT) run += deg[idx];
  }
}

// scatter: csr_dst[p] = dst[e]; pos[e] = p  (so edge pass can write weights in CSR order)
__global__ void scatter_kernel(const int* __restrict__ src, const int* __restrict__ dst,
                               int* __restrict__ cursor, int* __restrict__ csr_dst,
                               int* __restrict__ pos) {
  int e = blockIdx.x * blockDim.x + threadIdx.x;
  if (e >= N_EDGE) return;
  int p = atomicAdd(&cursor[src[e]], 1);
  csr_dst[p] = dst[e];
  pos[e] = p;
}

// ================= fused LayerNorm + node scores (s_h, s_t) =================
// W_h,W_t staged once per block (64KB LDS); waves grid-stride over nodes.
__global__ __launch_bounds__(512) void ln_scores_kernel(
    const float* __restrict__ x, const float* __restrict__ g, const float* __restrict__ b,
    const float* __restrict__ Wh, const float* __restrict__ Wt,
    const float* __restrict__ ah, const float* __restrict__ at,
    float* __restrict__ h, float* __restrict__ s_h, float* __restrict__ s_t) {
  __shared__ float Whs[64][128];
  __shared__ float Wts[64][128];
  __shared__ float ahs[128];
  __shared__ float ats[128];
  for (int i = threadIdx.x; i < 64 * 128; i += 512) {
    Whs[i >> 7][i & 127] = Wh[i];
    Wts[i >> 7][i & 127] = Wt[i];
  }
  if (threadIdx.x < 128) {
    ahs[threadIdx.x] = ah[threadIdx.x];
    ats[threadIdx.x] = at[threadIdx.x];
  }
  __syncthreads();
  int lane = threadIdx.x & 63;
  int gw = (blockIdx.x * 512 + threadIdx.x) >> 6;
  int nw = (gridDim.x * 512) >> 6;
  float gg = g[lane], bb = b[lane];
  for (int n = gw; n < N_ENT; n += nw) {
    float v = x[n * 64 + lane];
    float s = v;
#pragma unroll
    for (int off = 32; off; off >>= 1) s += __shfl_xor(s, off);
    float mu = s * (1.0f / 64.0f);
    float dv = v - mu;
    float s2 = dv * dv;
#pragma unroll
    for (int off = 32; off; off >>= 1) s2 += __shfl_xor(s2, off);
    float rs = rsqrtf(s2 * (1.0f / 64.0f) + LN_EPS);
    float hv = dv * rs * gg + bb;
    h[n * 64 + lane] = hv;
    float a0 = 0.f, a1 = 0.f, a2 = 0.f, a3 = 0.f;
#pragma unroll 16
    for (int k = 0; k < 64; ++k) {
      float bv = __shfl(hv, k);
      a0 += bv * Whs[k][lane];
      a1 += bv * Whs[k][lane + 64];
      a2 += bv * Wts[k][lane];
      a3 += bv * Wts[k][lane + 64];
    }
    float t0 = tanhf(a0) * ahs[lane];
    float t1 = tanhf(a1) * ahs[lane + 64];
    float t2 = tanhf(a2) * ats[lane];
    float t3 = tanhf(a3) * ats[lane + 64];
#pragma unroll
    for (int off = 32; off; off >>= 1) {
      t0 += __shfl_xor(t0, off);
      t1 += __shfl_xor(t1, off);
      t2 += __shfl_xor(t2, off);
      t3 += __shfl_xor(t3, off);
    }
    if (lane == 0) {
      ((float2*)s_h)[n] = make_float2(t0, t1);
      ((float2*)s_t)[n] = make_float2(t2, t3);
    }
  }
}

// ---- single-matrix scores (for relations; no LN) ----
__global__ __launch_bounds__(256) void scores1_kernel(
    const float* __restrict__ x, const float* __restrict__ W,
    const float* __restrict__ att, float* __restrict__ s_out, int M) {
  __shared__ float Ws[64][128];
  __shared__ float atts[128];
  for (int i = threadIdx.x; i < 64 * 128; i += 256) Ws[i >> 7][i & 127] = W[i];
  if (threadIdx.x < 128) atts[threadIdx.x] = att[threadIdx.x];
  __syncthreads();
  int lane = threadIdx.x & 63;
  int gw = (blockIdx.x * 256 + threadIdx.x) >> 6;
  int nw = (gridDim.x * 256) >> 6;
  for (int n = gw; n < M; n += nw) {
    float hv = x[n * 64 + lane];
    float a0 = 0.f, a1 = 0.f;
#pragma unroll 16
    for (int k = 0; k < 64; ++k) {
      float bv = __shfl(hv, k);
      a0 += bv * Ws[k][lane];
      a1 += bv * Ws[k][lane + 64];
    }
    float t0 = tanhf(a0) * atts[lane];
    float t1 = tanhf(a1) * atts[lane + 64];
#pragma unroll
    for (int off = 32; off; off >>= 1) {
      t0 += __shfl_xor(t0, off);
      t1 += __shfl_xor(t1, off);
    }
    if (lane == 0) ((float2*)s_out)[n] = make_float2(t0, t1);
  }
}

// ================= fused edge pass: score -> leaky_relu -> exp -> csr_w + z =================
// No max-subtraction: scores are bounded (|s| <~ 8), exp is safe in f32, ratios identical.
__global__ void edge_kernel(const int* __restrict__ src, const int* __restrict__ dst,
                            const int* __restrict__ et, const float* __restrict__ s_h,
                            const float* __restrict__ s_t, const float* __restrict__ s_r,
                            const int* __restrict__ pos, float* __restrict__ csr_w,
                            float* __restrict__ z) {
  int e = blockIdx.x * blockDim.x + threadIdx.x;
  if (e >= N_EDGE) return;
  int s = src[e], d = dst[e], r = et[e];
  float2 a = ((const float2*)s_h)[s];
  float2 b = ((const float2*)s_t)[d];
  float2 c = ((const float2*)s_r)[r];
  float sc0 = a.x + b.x + c.x;
  float sc1 = a.y + b.y + c.y;
  sc0 = (sc0 >= 0.f) ? sc0 : 0.01f * sc0;
  sc1 = (sc1 >= 0.f) ? sc1 : 0.01f * sc1;
  float w0 = expf(sc0), w1 = expf(sc1);
  ((float2*)csr_w)[pos[e]] = make_float2(w0, w1);
  atomicAdd(&z[s * 2 + 0], w0);
  atomicAdd(&z[s * 2 + 1], w1);
}

// ================= CSR SpMM: wave per node, 2 dims per lane =================
// Zout[n,:] = alpha*h[n] (bcast heads) + ((1-alpha)/z[n,hh]) * sum_p w_p * Zin[dst_p,:]
__global__ __launch_bounds__(256) void spmm_kernel(
    const int* __restrict__ rowptr, const int* __restrict__ csr_dst,
    const float* __restrict__ csr_w, const float* __restrict__ z,
    const float* __restrict__ h, const float* __restrict__ Zin,
    float* __restrict__ Zout, int zin_is_h) {
  int lane = threadIdx.x & 63;
  int gw = (blockIdx.x * 256 + threadIdx.x) >> 6;
  int nw = (gridDim.x * 256) >> 6;
  int hh = lane >> 5;            // head owning dims {2*lane, 2*lane+1}
  int dd = (2 * lane) & 63;      // dim within head
  for (int n = gw; n < N_ENT; n += nw) {
    int p0 = rowptr[n], p1 = rowptr[n + 1];
    float accx = 0.f, accy = 0.f;
    if (zin_is_h) {
      for (int p = p0; p < p1; ++p) {
        int d = csr_dst[p];
        float2 w2 = ((const float2*)csr_w)[p];
        float a = hh ? w2.y : w2.x;
        float2 zv = ((const float2*)(h + d * 64))[lane & 31];
        accx += a * zv.x;
        accy += a * zv.y;
      }
    } else {
      for (int p = p0; p < p1; ++p) {
        int d = csr_dst[p];
        float2 w2 = ((const float2*)csr_w)[p];
        float a = hh ? w2.y : w2.x;
        float2 zv = ((const float2*)(Zin + d * 128))[lane];
        accx += a * zv.x;
        accy += a * zv.y;
      }
    }
    float c = (p1 > p0) ? (1.0f - ALPHA) / z[n * 2 + hh] : 0.f;
    float2 hv = ((const float2*)(h + n * 64))[lane & 31];
    ((float2*)(Zout + n * 128))[lane] =
        make_float2(accx * c + ALPHA * hv.x, accy * c + ALPHA * hv.y);
  }
}

// ================= output: out = Z @ W_o + x ; waves grid-stride, Wo staged once =================
__global__ __launch_bounds__(512) void out_kernel(
    const float* __restrict__ Z, const float* __restrict__ Wo,
    const float* __restrict__ x, float* __restrict__ out) {
  __shared__ float Wos[128][64];
  for (int i = threadIdx.x; i < 128 * 64; i += 512) Wos[i >> 6][i & 63] = Wo[i];
  __syncthreads();
  int lane = threadIdx.x & 63;
  int gw = (blockIdx.x * 512 + threadIdx.x) >> 6;
  int nw = (gridDim.x * 512) >> 6;
  for (int n = gw; n < N_ENT; n += nw) {
    float zlo = Z[n * 128 + lane];
    float zhi = Z[n * 128 + 64 + lane];
    float acc = 0.f;
#pragma unroll 16
    for (int c = 0; c < 64; ++c) {
      acc += __shfl(zlo, c) * Wos[c][lane];
      acc += __shfl(zhi, c) * Wos[64 + c][lane];
    }
    out[n * 64 + lane] = acc + x[n * 64 + lane];
  }
}

extern "C" void kernel_launch(void* const* d_in, const int* in_sizes, int n_in,
                              void* d_out, int out_size, void* d_ws, size_t ws_size,
                              hipStream_t stream) {
  const float* ent0 = (const float*)d_in[0];
  const float* rel  = (const float*)d_in[1];
  const int* eidx   = (const int*)d_in[2];
  const int* src    = eidx;
  const int* dst    = eidx + N_EDGE;
  const int* et     = (const int*)d_in[3];
  const float* gam  = (const float*)d_in[4];
  const float* bet  = (const float*)d_in[5];
  const float* W_h  = (const float*)d_in[6];
  const float* W_t  = (const float*)d_in[7];
  const float* W_r  = (const float*)d_in[8];
  const float* att_h = (const float*)d_in[9];
  const float* att_t = (const float*)d_in[10];
  const float* att_r = (const float*)d_in[11];
  const float* W_o  = (const float*)d_in[12];
  float* outp = (float*)d_out;

  char* w = (char*)d_ws;
  auto alloc = [&](size_t bytes) {
    char* p = w;
    w += (bytes + 255) & ~(size_t)255;
    return p;
  };
  float* ent1   = (float*)alloc((size_t)N_ENT * 64 * 4);
  float* h      = (float*)alloc((size_t)N_ENT * 64 * 4);
  float* s_h    = (float*)alloc((size_t)N_ENT * 2 * 4);
  float* s_t    = (float*)alloc((size_t)N_ENT * 2 * 4);
  float* s_r    = (float*)alloc((size_t)N_REL * 2 * 4);
  float* z      = (float*)alloc((size_t)N_ENT * 2 * 4);
  float* csr_w  = (float*)alloc((size_t)N_EDGE * 2 * 4);
  float* Zb0    = (float*)alloc((size_t)N_ENT * 128 * 4);
  float* Zb1    = (float*)alloc((size_t)N_ENT * 128 * 4);
  int* deg      = (int*)alloc((size_t)N_ENT * 4);
  int* rowptr   = (int*)alloc((size_t)(N_ENT + 1) * 4);
  int* cursor   = (int*)alloc((size_t)N_ENT * 4);
  int* csr_dst  = (int*)alloc((size_t)N_EDGE * 4);
  int* pos      = (int*)alloc((size_t)N_EDGE * 4);

  const int EB = (N_EDGE + 255) / 256;

  // ---- CSR build ----
  hipMemsetAsync(deg, 0, (size_t)N_ENT * 4, stream);
  deg_kernel<<<EB, 256, 0, stream>>>(src, deg);
  scan_kernel<<<1, 1024, 0, stream>>>(deg, rowptr);
  hipMemcpyAsync(cursor, rowptr, (size_t)N_ENT * 4, hipMemcpyDeviceToDevice, stream);
  scatter_kernel<<<EB, 256, 0, stream>>>(src, dst, cursor, csr_dst, pos);

  for (int l = 0; l < 2; ++l) {
    const float* x = (l == 0) ? ent0 : ent1;
    float* y = (l == 0) ? ent1 : outp;

    ln_scores_kernel<<<512, 512, 0, stream>>>(x, gam + l * 64, bet + l * 64,
                                              W_h + l * 8192, W_t + l * 8192,
                                              att_h + l * 128, att_t + l * 128,
                                              h, s_h, s_t);
    scores1_kernel<<<8, 256, 0, stream>>>(rel, W_r + l * 8192, att_r + l * 128, s_r, N_REL);

    hipMemsetAsync(z, 0, (size_t)N_ENT * 2 * 4, stream);
    edge_kernel<<<EB, 256, 0, stream>>>(src, dst, et, s_h, s_t, s_r, pos, csr_w, z);

    // ---- PPR power iteration: 3 gather-SpMMs (initZ + norm fused) ----
    spmm_kernel<<<2048, 256, 0, stream>>>(rowptr, csr_dst, csr_w, z, h, h, Zb0, 1);
    spmm_kernel<<<2048, 256, 0, stream>>>(rowptr, csr_dst, csr_w, z, h, Zb0, Zb1, 0);
    spmm_kernel<<<2048, 256, 0, stream>>>(rowptr, csr_dst, csr_w, z, h, Zb1, Zb0, 0);

    out_kernel<<<1024, 512, 0, stream>>>(Zb0, W_o + l * 8192, x, y);
  }
}

// Round 4
// 931.736 us; speedup vs baseline: 2.7003x; 1.1898x over previous
//
#include <hip/hip_runtime.h>

#define N_ENT 50000
#define N_REL 500
#define N_EDGE 500000
#define HEADS 2
#define DIM 64
#define POW_ITER 3
#define ALPHA 0.15f
#define LN_EPS 1e-5f

// ================= CSR build (once per launch; graph is layer-invariant) =================
__global__ void deg_kernel(const int* __restrict__ src, int* __restrict__ deg) {
  int e = blockIdx.x * blockDim.x + threadIdx.x;
  if (e >= N_EDGE) return;
  atomicAdd(&deg[src[e]], 1);
}

// single-block exclusive scan of deg[0..N_ENT) -> rowptr[0..N_ENT]
__global__ void scan_kernel(const int* __restrict__ deg, int* __restrict__ rowptr) {
  __shared__ int sums[1024];
  int t = threadIdx.x;
  const int C = (N_ENT + 1023) / 1024;  // 49
  int base = t * C;
  int s = 0;
  for (int i = 0; i < C; ++i) {
    int idx = base + i;
    if (idx < N_ENT) s += deg[idx];
  }
  sums[t] = s;
  __syncthreads();
  for (int off = 1; off < 1024; off <<= 1) {
    int v = (t >= off) ? sums[t - off] : 0;
    __syncthreads();
    sums[t] += v;
    __syncthreads();
  }
  int run = (t == 0) ? 0 : sums[t - 1];
  for (int i = 0; i < C; ++i) {
    int idx = base + i;
    if (idx <= N_ENT) rowptr[idx] = run;
    if (idx < N_ENT) run += deg[idx];
  }
}

// scatter: csr_dst[p] = dst[e]; pos[e] = p  (so edge pass can write weights in CSR order)
__global__ void scatter_kernel(const int* __restrict__ src, const int* __restrict__ dst,
                               int* __restrict__ cursor, int* __restrict__ csr_dst,
                               int* __restrict__ pos) {
  int e = blockIdx.x * blockDim.x + threadIdx.x;
  if (e >= N_EDGE) return;
  int p = atomicAdd(&cursor[src[e]], 1);
  csr_dst[p] = dst[e];
  pos[e] = p;
}

// ================= fused LayerNorm + node scores (s_h, s_t) =================
// Wf[k][lane] = {Wh[k][lane], Wh[k][lane+64], Wt[k][lane], Wt[k][lane+64]} -> 1 ds_read_b128/k
// 2 nodes per wave: W read amortized over 8 FMAs.
__global__ __launch_bounds__(512) void ln_scores_kernel(
    const float* __restrict__ x, const float* __restrict__ g, const float* __restrict__ b,
    const float* __restrict__ Wh, const float* __restrict__ Wt,
    const float* __restrict__ ah, const float* __restrict__ at,
    float* __restrict__ h, float* __restrict__ s_h, float* __restrict__ s_t) {
  __shared__ float4 Wf[64][64];
  __shared__ float4 attf[64];
  for (int i = threadIdx.x; i < 64 * 64; i += 512) {
    int k = i >> 6, c = i & 63;
    Wf[k][c] = make_float4(Wh[k * 128 + c], Wh[k * 128 + c + 64],
                           Wt[k * 128 + c], Wt[k * 128 + c + 64]);
  }
  if (threadIdx.x < 64)
    attf[threadIdx.x] = make_float4(ah[threadIdx.x], ah[threadIdx.x + 64],
                                    at[threadIdx.x], at[threadIdx.x + 64]);
  __syncthreads();
  int lane = threadIdx.x & 63;
  int gw = (blockIdx.x * 512 + threadIdx.x) >> 6;
  int nw = (gridDim.x * 512) >> 6;
  float gg = g[lane], bb = b[lane];
  // N_ENT is even, n0 always even -> n0+1 always valid
  for (int n0 = 2 * gw; n0 < N_ENT; n0 += 2 * nw) {
    int n1 = n0 + 1;
    float v0 = x[n0 * 64 + lane];
    float v1 = x[n1 * 64 + lane];
    float s0 = v0, s1 = v1;
#pragma unroll
    for (int off = 32; off; off >>= 1) {
      s0 += __shfl_xor(s0, off);
      s1 += __shfl_xor(s1, off);
    }
    float d0 = v0 - s0 * (1.0f / 64.0f);
    float d1 = v1 - s1 * (1.0f / 64.0f);
    float q0 = d0 * d0, q1 = d1 * d1;
#pragma unroll
    for (int off = 32; off; off >>= 1) {
      q0 += __shfl_xor(q0, off);
      q1 += __shfl_xor(q1, off);
    }
    float hv0 = d0 * rsqrtf(q0 * (1.0f / 64.0f) + LN_EPS) * gg + bb;
    float hv1 = d1 * rsqrtf(q1 * (1.0f / 64.0f) + LN_EPS) * gg + bb;
    h[n0 * 64 + lane] = hv0;
    h[n1 * 64 + lane] = hv1;
    float a0 = 0.f, a1 = 0.f, a2 = 0.f, a3 = 0.f;
    float c0 = 0.f, c1 = 0.f, c2 = 0.f, c3 = 0.f;
#pragma unroll 16
    for (int k = 0; k < 64; ++k) {
      float4 wv = Wf[k][lane];
      float f0 = __shfl(hv0, k);
      float f1 = __shfl(hv1, k);
      a0 += f0 * wv.x; a1 += f0 * wv.y; a2 += f0 * wv.z; a3 += f0 * wv.w;
      c0 += f1 * wv.x; c1 += f1 * wv.y; c2 += f1 * wv.z; c3 += f1 * wv.w;
    }
    float4 av = attf[lane];
    float ta0 = tanhf(a0) * av.x, ta1 = tanhf(a1) * av.y;
    float ta2 = tanhf(a2) * av.z, ta3 = tanhf(a3) * av.w;
    float tb0 = tanhf(c0) * av.x, tb1 = tanhf(c1) * av.y;
    float tb2 = tanhf(c2) * av.z, tb3 = tanhf(c3) * av.w;
#pragma unroll
    for (int off = 32; off; off >>= 1) {
      ta0 += __shfl_xor(ta0, off); ta1 += __shfl_xor(ta1, off);
      ta2 += __shfl_xor(ta2, off); ta3 += __shfl_xor(ta3, off);
      tb0 += __shfl_xor(tb0, off); tb1 += __shfl_xor(tb1, off);
      tb2 += __shfl_xor(tb2, off); tb3 += __shfl_xor(tb3, off);
    }
    if (lane == 0) {
      ((float2*)s_h)[n0] = make_float2(ta0, ta1);
      ((float2*)s_t)[n0] = make_float2(ta2, ta3);
      ((float2*)s_h)[n1] = make_float2(tb0, tb1);
      ((float2*)s_t)[n1] = make_float2(tb2, tb3);
    }
  }
}

// ---- single-matrix scores (for relations; no LN) ----
__global__ __launch_bounds__(256) void scores1_kernel(
    const float* __restrict__ x, const float* __restrict__ W,
    const float* __restrict__ att, float* __restrict__ s_out, int M) {
  __shared__ float2 Ws[64][64];
  __shared__ float2 atts[64];
  for (int i = threadIdx.x; i < 64 * 64; i += 256) {
    int k = i >> 6, c = i & 63;
    Ws[k][c] = make_float2(W[k * 128 + c], W[k * 128 + c + 64]);
  }
  if (threadIdx.x < 64)
    atts[threadIdx.x] = make_float2(att[threadIdx.x], att[threadIdx.x + 64]);
  __syncthreads();
  int lane = threadIdx.x & 63;
  int gw = (blockIdx.x * 256 + threadIdx.x) >> 6;
  int nw = (gridDim.x * 256) >> 6;
  for (int n = gw; n < M; n += nw) {
    float hv = x[n * 64 + lane];
    float a0 = 0.f, a1 = 0.f;
#pragma unroll 16
    for (int k = 0; k < 64; ++k) {
      float2 wv = Ws[k][lane];
      float bv = __shfl(hv, k);
      a0 += bv * wv.x;
      a1 += bv * wv.y;
    }
    float2 av = atts[lane];
    float t0 = tanhf(a0) * av.x;
    float t1 = tanhf(a1) * av.y;
#pragma unroll
    for (int off = 32; off; off >>= 1) {
      t0 += __shfl_xor(t0, off);
      t1 += __shfl_xor(t1, off);
    }
    if (lane == 0) ((float2*)s_out)[n] = make_float2(t0, t1);
  }
}

// ================= fused edge pass: score -> leaky_relu -> exp -> csr_w + z =================
__global__ void edge_kernel(const int* __restrict__ src, const int* __restrict__ dst,
                            const int* __restrict__ et, const float* __restrict__ s_h,
                            const float* __restrict__ s_t, const float* __restrict__ s_r,
                            const int* __restrict__ pos, float* __restrict__ csr_w,
                            float* __restrict__ z) {
  int e = blockIdx.x * blockDim.x + threadIdx.x;
  if (e >= N_EDGE) return;
  int s = src[e], d = dst[e], r = et[e];
  float2 a = ((const float2*)s_h)[s];
  float2 b = ((const float2*)s_t)[d];
  float2 c = ((const float2*)s_r)[r];
  float sc0 = a.x + b.x + c.x;
  float sc1 = a.y + b.y + c.y;
  sc0 = (sc0 >= 0.f) ? sc0 : 0.01f * sc0;
  sc1 = (sc1 >= 0.f) ? sc1 : 0.01f * sc1;
  float w0 = expf(sc0), w1 = expf(sc1);
  ((float2*)csr_w)[pos[e]] = make_float2(w0, w1);
  atomicAdd(&z[s * 2 + 0], w0);
  atomicAdd(&z[s * 2 + 1], w1);
}

// ================= CSR SpMM: wave per node; 2 edge slots (half-waves) x float4 dims =================
__global__ __launch_bounds__(256) void spmm_kernel(
    const int* __restrict__ rowptr, const int* __restrict__ csr_dst,
    const float* __restrict__ csr_w, const float* __restrict__ z,
    const float* __restrict__ h, const float* __restrict__ Zin,
    float* __restrict__ Zout, int zin_is_h) {
  int lane = threadIdx.x & 63;
  int half = lane >> 5;       // edge slot
  int l4 = lane & 31;         // dim group: dims 4*l4 .. 4*l4+3
  int hh = l4 >> 4;           // head
  int hd = (4 * l4) & 63;     // dim within h row
  int gw = (blockIdx.x * 256 + threadIdx.x) >> 6;
  int nw = (gridDim.x * 256) >> 6;
  for (int n = gw; n < N_ENT; n += nw) {
    int p0 = rowptr[n], p1 = rowptr[n + 1];
    float4 acc = make_float4(0.f, 0.f, 0.f, 0.f);
    if (zin_is_h) {
      for (int p = p0 + half; p < p1; p += 2) {
        int d = csr_dst[p];
        float2 w2 = ((const float2*)csr_w)[p];
        float a = hh ? w2.y : w2.x;
        float4 zv = *(const float4*)(h + d * 64 + hd);
        acc.x += a * zv.x; acc.y += a * zv.y; acc.z += a * zv.z; acc.w += a * zv.w;
      }
    } else {
      for (int p = p0 + half; p < p1; p += 2) {
        int d = csr_dst[p];
        float2 w2 = ((const float2*)csr_w)[p];
        float a = hh ? w2.y : w2.x;
        float4 zv = ((const float4*)(Zin + d * 128))[l4];
        acc.x += a * zv.x; acc.y += a * zv.y; acc.z += a * zv.z; acc.w += a * zv.w;
      }
    }
    acc.x += __shfl_xor(acc.x, 32);
    acc.y += __shfl_xor(acc.y, 32);
    acc.z += __shfl_xor(acc.z, 32);
    acc.w += __shfl_xor(acc.w, 32);
    if (half == 0) {
      float c = (p1 > p0) ? (1.0f - ALPHA) / z[n * 2 + hh] : 0.f;
      float4 hv = *(const float4*)(h + n * 64 + hd);
      float4 o;
      o.x = acc.x * c + ALPHA * hv.x;
      o.y = acc.y * c + ALPHA * hv.y;
      o.z = acc.z * c + ALPHA * hv.z;
      o.w = acc.w * c + ALPHA * hv.w;
      ((float4*)(Zout + n * 128))[l4] = o;
    }
  }
}

// ================= output: out = Z @ W_o + x ; WoI[c][lane] = {Wo[c][lane], Wo[c+64][lane]} =================
__global__ __launch_bounds__(512) void out_kernel(
    const float* __restrict__ Z, const float* __restrict__ Wo,
    const float* __restrict__ x, float* __restrict__ out) {
  __shared__ float2 WoI[64][64];
  for (int i = threadIdx.x; i < 64 * 64; i += 512) {
    int c = i >> 6, lane = i & 63;
    WoI[c][lane] = make_float2(Wo[c * 64 + lane], Wo[(c + 64) * 64 + lane]);
  }
  __syncthreads();
  int lane = threadIdx.x & 63;
  int gw = (blockIdx.x * 512 + threadIdx.x) >> 6;
  int nw = (gridDim.x * 512) >> 6;
  for (int n = gw; n < N_ENT; n += nw) {
    float zlo = Z[n * 128 + lane];
    float zhi = Z[n * 128 + 64 + lane];
    float acc = 0.f;
#pragma unroll 16
    for (int c = 0; c < 64; ++c) {
      float2 wv = WoI[c][lane];
      acc += __shfl(zlo, c) * wv.x;
      acc += __shfl(zhi, c) * wv.y;
    }
    out[n * 64 + lane] = acc + x[n * 64 + lane];
  }
}

extern "C" void kernel_launch(void* const* d_in, const int* in_sizes, int n_in,
                              void* d_out, int out_size, void* d_ws, size_t ws_size,
                              hipStream_t stream) {
  const float* ent0 = (const float*)d_in[0];
  const float* rel  = (const float*)d_in[1];
  const int* eidx   = (const int*)d_in[2];
  const int* src    = eidx;
  const int* dst    = eidx + N_EDGE;
  const int* et     = (const int*)d_in[3];
  const float* gam  = (const float*)d_in[4];
  const float* bet  = (const float*)d_in[5];
  const float* W_h  = (const float*)d_in[6];
  const float* W_t  = (const float*)d_in[7];
  const float* W_r  = (const float*)d_in[8];
  const float* att_h = (const float*)d_in[9];
  const float* att_t = (const float*)d_in[10];
  const float* att_r = (const float*)d_in[11];
  const float* W_o  = (const float*)d_in[12];
  float* outp = (float*)d_out;

  char* w = (char*)d_ws;
  auto alloc = [&](size_t bytes) {
    char* p = w;
    w += (bytes + 255) & ~(size_t)255;
    return p;
  };
  float* ent1   = (float*)alloc((size_t)N_ENT * 64 * 4);
  float* h      = (float*)alloc((size_t)N_ENT * 64 * 4);
  float* s_h    = (float*)alloc((size_t)N_ENT * 2 * 4);
  float* s_t    = (float*)alloc((size_t)N_ENT * 2 * 4);
  float* s_r    = (float*)alloc((size_t)N_REL * 2 * 4);
  float* z      = (float*)alloc((size_t)N_ENT * 2 * 4);
  float* csr_w  = (float*)alloc((size_t)N_EDGE * 2 * 4);
  float* Zb0    = (float*)alloc((size_t)N_ENT * 128 * 4);
  float* Zb1    = (float*)alloc((size_t)N_ENT * 128 * 4);
  int* deg      = (int*)alloc((size_t)N_ENT * 4);
  int* rowptr   = (int*)alloc((size_t)(N_ENT + 1) * 4);
  int* cursor   = (int*)alloc((size_t)N_ENT * 4);
  int* csr_dst  = (int*)alloc((size_t)N_EDGE * 4);
  int* pos      = (int*)alloc((size_t)N_EDGE * 4);

  const int EB = (N_EDGE + 255) / 256;

  // ---- CSR build ----
  hipMemsetAsync(deg, 0, (size_t)N_ENT * 4, stream);
  deg_kernel<<<EB, 256, 0, stream>>>(src, deg);
  scan_kernel<<<1, 1024, 0, stream>>>(deg, rowptr);
  hipMemcpyAsync(cursor, rowptr, (size_t)N_ENT * 4, hipMemcpyDeviceToDevice, stream);
  scatter_kernel<<<EB, 256, 0, stream>>>(src, dst, cursor, csr_dst, pos);

  for (int l = 0; l < 2; ++l) {
    const float* x = (l == 0) ? ent0 : ent1;
    float* y = (l == 0) ? ent1 : outp;

    ln_scores_kernel<<<512, 512, 0, stream>>>(x, gam + l * 64, bet + l * 64,
                                              W_h + l * 8192, W_t + l * 8192,
                                              att_h + l * 128, att_t + l * 128,
                                              h, s_h, s_t);
    scores1_kernel<<<8, 256, 0, stream>>>(rel, W_r + l * 8192, att_r + l * 128, s_r, N_REL);

    hipMemsetAsync(z, 0, (size_t)N_ENT * 2 * 4, stream);
    edge_kernel<<<EB, 256, 0, stream>>>(src, dst, et, s_h, s_t, s_r, pos, csr_w, z);

    // ---- PPR power iteration: 3 gather-SpMMs (initZ + norm fused) ----
    spmm_kernel<<<2048, 256, 0, stream>>>(rowptr, csr_dst, csr_w, z, h, h, Zb0, 1);
    spmm_kernel<<<2048, 256, 0, stream>>>(rowptr, csr_dst, csr_w, z, h, Zb0, Zb1, 0);
    spmm_kernel<<<2048, 256, 0, stream>>>(rowptr, csr_dst, csr_w, z, h, Zb1, Zb0, 0);

    out_kernel<<<1024, 512, 0, stream>>>(Zb0, W_o + l * 8192, x, y);
  }
}

// Round 5
// 781.073 us; speedup vs baseline: 3.2212x; 1.1929x over previous
//
#include <hip/hip_runtime.h>

#define N_ENT 50000
#define N_REL 500
#define N_EDGE 500000
#define HEADS 2
#define DIM 64
#define POW_ITER 3
#define ALPHA 0.15f
#define LN_EPS 1e-5f

// ================= CSR build (once per launch; graph is layer-invariant) =================
__global__ void deg_kernel(const int* __restrict__ src, int* __restrict__ deg) {
  int e = blockIdx.x * blockDim.x + threadIdx.x;
  if (e >= N_EDGE) return;
  atomicAdd(&deg[src[e]], 1);
}

// single-block exclusive scan of deg[0..N_ENT) -> rowptr[0..N_ENT]
__global__ void scan_kernel(const int* __restrict__ deg, int* __restrict__ rowptr) {
  __shared__ int sums[1024];
  int t = threadIdx.x;
  const int C = (N_ENT + 1023) / 1024;  // 49
  int base = t * C;
  int s = 0;
  for (int i = 0; i < C; ++i) {
    int idx = base + i;
    if (idx < N_ENT) s += deg[idx];
  }
  sums[t] = s;
  __syncthreads();
  for (int off = 1; off < 1024; off <<= 1) {
    int v = (t >= off) ? sums[t - off] : 0;
    __syncthreads();
    sums[t] += v;
    __syncthreads();
  }
  int run = (t == 0) ? 0 : sums[t - 1];
  for (int i = 0; i < C; ++i) {
    int idx = base + i;
    if (idx <= N_ENT) rowptr[idx] = run;
    if (idx < N_ENT) run += deg[idx];
  }
}

// scatter: csr_dst[p] = dst[e]; pos[e] = p
__global__ void scatter_kernel(const int* __restrict__ src, const int* __restrict__ dst,
                               int* __restrict__ cursor, int* __restrict__ csr_dst,
                               int* __restrict__ pos) {
  int e = blockIdx.x * blockDim.x + threadIdx.x;
  if (e >= N_EDGE) return;
  int p = atomicAdd(&cursor[src[e]], 1);
  csr_dst[p] = dst[e];
  pos[e] = p;
}

// ================= LayerNorm: one wave per node =================
__global__ void ln_kernel(const float* __restrict__ x, const float* __restrict__ g,
                          const float* __restrict__ b, float* __restrict__ h) {
  int wid = (blockIdx.x * blockDim.x + threadIdx.x) >> 6;
  int lane = threadIdx.x & 63;
  if (wid >= N_ENT) return;
  float v = x[wid * 64 + lane];
  float s = v;
#pragma unroll
  for (int off = 32; off; off >>= 1) s += __shfl_xor(s, off);
  float mu = s * (1.0f / 64.0f);
  float d = v - mu;
  float s2 = d * d;
#pragma unroll
  for (int off = 32; off; off >>= 1) s2 += __shfl_xor(s2, off);
  float rs = rsqrtf(s2 * (1.0f / 64.0f) + LN_EPS);
  h[wid * 64 + lane] = d * rs * g[lane] + b[lane];
}

// ================= node scores: W column in VGPRs, x row via scalar loads =================
// lane j holds W[k][j] (w0) and W[k][j+64] (w1) for all k. Per node: 128 FMA w/ SGPR
// broadcast operand, tanh, 12-shfl wave reduce.
__global__ __launch_bounds__(256) void scores_w_kernel(
    const float* __restrict__ x, const float* __restrict__ W,
    const float* __restrict__ att, float* __restrict__ s_out, int M) {
  int lane = threadIdx.x & 63;
  float w0[64], w1[64];
#pragma unroll
  for (int k = 0; k < 64; ++k) {
    w0[k] = W[k * 128 + lane];
    w1[k] = W[k * 128 + lane + 64];
  }
  float a0v = att[lane], a1v = att[lane + 64];
  int gw = (blockIdx.x * 256 + threadIdx.x) >> 6;
  int nw = (gridDim.x * 256) >> 6;
  for (int n = gw; n < M; n += nw) {
    int nu = __builtin_amdgcn_readfirstlane(n);
    const float* xr = x + nu * 64;
    float p0 = 0.f, p1 = 0.f, p2 = 0.f, p3 = 0.f;
#pragma unroll
    for (int k = 0; k < 32; ++k) {
      float xa = xr[k], xb = xr[k + 32];
      p0 += xa * w0[k];
      p1 += xb * w0[k + 32];
      p2 += xa * w1[k];
      p3 += xb * w1[k + 32];
    }
    float t0 = tanhf(p0 + p1) * a0v;
    float t1 = tanhf(p2 + p3) * a1v;
#pragma unroll
    for (int off = 32; off; off >>= 1) {
      t0 += __shfl_xor(t0, off);
      t1 += __shfl_xor(t1, off);
    }
    if (lane == 0) ((float2*)s_out)[nu] = make_float2(t0, t1);
  }
}

// ================= fused edge pass: score -> leaky_relu -> exp -> csr_w + z =================
__global__ void edge_kernel(const int* __restrict__ src, const int* __restrict__ dst,
                            const int* __restrict__ et, const float* __restrict__ s_h,
                            const float* __restrict__ s_t, const float* __restrict__ s_r,
                            const int* __restrict__ pos, float* __restrict__ csr_w,
                            float* __restrict__ z) {
  int e = blockIdx.x * blockDim.x + threadIdx.x;
  if (e >= N_EDGE) return;
  int s = src[e], d = dst[e], r = et[e];
  float2 a = ((const float2*)s_h)[s];
  float2 b = ((const float2*)s_t)[d];
  float2 c = ((const float2*)s_r)[r];
  float sc0 = a.x + b.x + c.x;
  float sc1 = a.y + b.y + c.y;
  sc0 = (sc0 >= 0.f) ? sc0 : 0.01f * sc0;
  sc1 = (sc1 >= 0.f) ? sc1 : 0.01f * sc1;
  float w0 = expf(sc0), w1 = expf(sc1);
  ((float2*)csr_w)[pos[e]] = make_float2(w0, w1);
  atomicAdd(&z[s * 2 + 0], w0);
  atomicAdd(&z[s * 2 + 1], w1);
}

// ================= CSR SpMM: wave per node; 4 edge slots (quarter-waves) x 8 dims =================
__global__ __launch_bounds__(256) void spmm_kernel(
    const int* __restrict__ rowptr, const int* __restrict__ csr_dst,
    const float* __restrict__ csr_w, const float* __restrict__ z,
    const float* __restrict__ h, const float* __restrict__ Zin,
    float* __restrict__ Zout, int zin_is_h) {
  int lane = threadIdx.x & 63;
  int slot = lane >> 4;        // 4 edge slots per wave
  int l16 = lane & 15;         // dims 8*l16 .. 8*l16+7
  int hh = l16 >> 3;           // head
  int hoff = 8 * (l16 & 7);    // offset within 64-dim head row
  int gw = (blockIdx.x * 256 + threadIdx.x) >> 6;
  int nw = (gridDim.x * 256) >> 6;
  for (int n = gw; n < N_ENT; n += nw) {
    int p0 = rowptr[n], p1 = rowptr[n + 1];
    float4 acc0 = make_float4(0.f, 0.f, 0.f, 0.f);
    float4 acc1 = make_float4(0.f, 0.f, 0.f, 0.f);
    if (zin_is_h) {
      for (int p = p0 + slot; p < p1; p += 4) {
        int d = csr_dst[p];
        float2 w2 = ((const float2*)csr_w)[p];
        float a = hh ? w2.y : w2.x;
        const float* zp = h + d * 64 + hoff;
        float4 z0 = *(const float4*)zp;
        float4 z1 = *(const float4*)(zp + 4);
        acc0.x += a * z0.x; acc0.y += a * z0.y; acc0.z += a * z0.z; acc0.w += a * z0.w;
        acc1.x += a * z1.x; acc1.y += a * z1.y; acc1.z += a * z1.z; acc1.w += a * z1.w;
      }
    } else {
      for (int p = p0 + slot; p < p1; p += 4) {
        int d = csr_dst[p];
        float2 w2 = ((const float2*)csr_w)[p];
        float a = hh ? w2.y : w2.x;
        const float* zp = Zin + d * 128 + 8 * l16;
        float4 z0 = *(const float4*)zp;
        float4 z1 = *(const float4*)(zp + 4);
        acc0.x += a * z0.x; acc0.y += a * z0.y; acc0.z += a * z0.z; acc0.w += a * z0.w;
        acc1.x += a * z1.x; acc1.y += a * z1.y; acc1.z += a * z1.z; acc1.w += a * z1.w;
      }
    }
#pragma unroll
    for (int off = 16; off <= 32; off <<= 1) {
      acc0.x += __shfl_xor(acc0.x, off); acc0.y += __shfl_xor(acc0.y, off);
      acc0.z += __shfl_xor(acc0.z, off); acc0.w += __shfl_xor(acc0.w, off);
      acc1.x += __shfl_xor(acc1.x, off); acc1.y += __shfl_xor(acc1.y, off);
      acc1.z += __shfl_xor(acc1.z, off); acc1.w += __shfl_xor(acc1.w, off);
    }
    if (slot == 0) {
      float c = (p1 > p0) ? (1.0f - ALPHA) / z[n * 2 + hh] : 0.f;
      const float* hp = h + n * 64 + hoff;
      float4 h0 = *(const float4*)hp;
      float4 h1 = *(const float4*)(hp + 4);
      float4 o0, o1;
      o0.x = acc0.x * c + ALPHA * h0.x; o0.y = acc0.y * c + ALPHA * h0.y;
      o0.z = acc0.z * c + ALPHA * h0.z; o0.w = acc0.w * c + ALPHA * h0.w;
      o1.x = acc1.x * c + ALPHA * h1.x; o1.y = acc1.y * c + ALPHA * h1.y;
      o1.z = acc1.z * c + ALPHA * h1.z; o1.w = acc1.w * c + ALPHA * h1.w;
      float* op = Zout + n * 128 + 8 * l16;
      *(float4*)op = o0;
      *(float4*)(op + 4) = o1;
    }
  }
}

// ================= output: lane = column j; W_o column in 128 VGPRs; Z row via s_load =================
__global__ __launch_bounds__(256) void out_kernel(
    const float* __restrict__ Z, const float* __restrict__ Wo,
    const float* __restrict__ x, float* __restrict__ out) {
  int lane = threadIdx.x & 63;
  float wo[128];
#pragma unroll
  for (int c = 0; c < 128; ++c) wo[c] = Wo[c * 64 + lane];
  int gw = (blockIdx.x * 256 + threadIdx.x) >> 6;
  int nw = (gridDim.x * 256) >> 6;
  for (int n = gw; n < N_ENT; n += nw) {
    int nu = __builtin_amdgcn_readfirstlane(n);
    const float* zr = Z + nu * 128;
    float a0 = 0.f, a1 = 0.f, a2 = 0.f, a3 = 0.f;
#pragma unroll
    for (int c = 0; c < 32; ++c) {
      a0 += zr[c] * wo[c];
      a1 += zr[c + 32] * wo[c + 32];
      a2 += zr[c + 64] * wo[c + 64];
      a3 += zr[c + 96] * wo[c + 96];
    }
    out[nu * 64 + lane] = (a0 + a1) + (a2 + a3) + x[nu * 64 + lane];
  }
}

extern "C" void kernel_launch(void* const* d_in, const int* in_sizes, int n_in,
                              void* d_out, int out_size, void* d_ws, size_t ws_size,
                              hipStream_t stream) {
  const float* ent0 = (const float*)d_in[0];
  const float* rel  = (const float*)d_in[1];
  const int* eidx   = (const int*)d_in[2];
  const int* src    = eidx;
  const int* dst    = eidx + N_EDGE;
  const int* et     = (const int*)d_in[3];
  const float* gam  = (const float*)d_in[4];
  const float* bet  = (const float*)d_in[5];
  const float* W_h  = (const float*)d_in[6];
  const float* W_t  = (const float*)d_in[7];
  const float* W_r  = (const float*)d_in[8];
  const float* att_h = (const float*)d_in[9];
  const float* att_t = (const float*)d_in[10];
  const float* att_r = (const float*)d_in[11];
  const float* W_o  = (const float*)d_in[12];
  float* outp = (float*)d_out;

  char* w = (char*)d_ws;
  auto alloc = [&](size_t bytes) {
    char* p = w;
    w += (bytes + 255) & ~(size_t)255;
    return p;
  };
  float* ent1   = (float*)alloc((size_t)N_ENT * 64 * 4);
  float* h      = (float*)alloc((size_t)N_ENT * 64 * 4);
  float* s_h    = (float*)alloc((size_t)N_ENT * 2 * 4);
  float* s_t    = (float*)alloc((size_t)N_ENT * 2 * 4);
  float* s_r    = (float*)alloc((size_t)N_REL * 2 * 4);
  float* z      = (float*)alloc((size_t)N_ENT * 2 * 4);
  float* csr_w  = (float*)alloc((size_t)N_EDGE * 2 * 4);
  float* Zb0    = (float*)alloc((size_t)N_ENT * 128 * 4);
  float* Zb1    = (float*)alloc((size_t)N_ENT * 128 * 4);
  int* deg      = (int*)alloc((size_t)N_ENT * 4);
  int* rowptr   = (int*)alloc((size_t)(N_ENT + 1) * 4);
  int* cursor   = (int*)alloc((size_t)N_ENT * 4);
  int* csr_dst  = (int*)alloc((size_t)N_EDGE * 4);
  int* pos      = (int*)alloc((size_t)N_EDGE * 4);

  const int EB = (N_EDGE + 255) / 256;

  // ---- CSR build ----
  hipMemsetAsync(deg, 0, (size_t)N_ENT * 4, stream);
  deg_kernel<<<EB, 256, 0, stream>>>(src, deg);
  scan_kernel<<<1, 1024, 0, stream>>>(deg, rowptr);
  hipMemcpyAsync(cursor, rowptr, (size_t)N_ENT * 4, hipMemcpyDeviceToDevice, stream);
  scatter_kernel<<<EB, 256, 0, stream>>>(src, dst, cursor, csr_dst, pos);

  for (int l = 0; l < 2; ++l) {
    const float* x = (l == 0) ? ent0 : ent1;
    float* y = (l == 0) ? ent1 : outp;

    ln_kernel<<<(N_ENT + 3) / 4, 256, 0, stream>>>(x, gam + l * 64, bet + l * 64, h);
    scores_w_kernel<<<1024, 256, 0, stream>>>(h, W_h + l * 8192, att_h + l * 128, s_h, N_ENT);
    scores_w_kernel<<<1024, 256, 0, stream>>>(h, W_t + l * 8192, att_t + l * 128, s_t, N_ENT);
    scores_w_kernel<<<8, 256, 0, stream>>>(rel, W_r + l * 8192, att_r + l * 128, s_r, N_REL);

    hipMemsetAsync(z, 0, (size_t)N_ENT * 2 * 4, stream);
    edge_kernel<<<EB, 256, 0, stream>>>(src, dst, et, s_h, s_t, s_r, pos, csr_w, z);

    // ---- PPR power iteration: 3 gather-SpMMs (initZ + norm fused) ----
    spmm_kernel<<<2048, 256, 0, stream>>>(rowptr, csr_dst, csr_w, z, h, h, Zb0, 1);
    spmm_kernel<<<2048, 256, 0, stream>>>(rowptr, csr_dst, csr_w, z, h, Zb0, Zb1, 0);
    spmm_kernel<<<2048, 256, 0, stream>>>(rowptr, csr_dst, csr_w, z, h, Zb1, Zb0, 0);

    out_kernel<<<512, 256, 0, stream>>>(Zb0, W_o + l * 8192, x, y);
  }
}

// Round 6
// 638.334 us; speedup vs baseline: 3.9415x; 1.2236x over previous
//
#include <hip/hip_runtime.h>

#define N_ENT 50000
#define N_REL 500
#define N_EDGE 500000
#define HEADS 2
#define DIM 64
#define POW_ITER 3
#define ALPHA 0.15f
#define LN_EPS 1e-5f
#define NBLK 49  // ceil(N_ENT/1024)

// bf16 round-to-nearest-even pack
static __device__ __forceinline__ unsigned bf16_rne(float f) {
  unsigned u = __float_as_uint(f);
  return (u + 0x7FFFu + ((u >> 16) & 1u)) >> 16;
}

// ================= CSR build (once per launch; graph is layer-invariant) =================
__global__ void deg_kernel(const int* __restrict__ src, int* __restrict__ deg) {
  int e = blockIdx.x * blockDim.x + threadIdx.x;
  if (e >= N_EDGE) return;
  atomicAdd(&deg[src[e]], 1);
}

// Phase 1: per-block (1024-wide) exclusive scan; block sums out
__global__ __launch_bounds__(1024) void scan1_kernel(const int* __restrict__ deg,
                                                     int* __restrict__ exc,
                                                     int* __restrict__ bsum) {
  __shared__ int tmp[1024];
  int tid = threadIdx.x;
  int i = blockIdx.x * 1024 + tid;
  int v = (i < N_ENT) ? deg[i] : 0;
  tmp[tid] = v;
  __syncthreads();
  for (int off = 1; off < 1024; off <<= 1) {
    int t = (tid >= off) ? tmp[tid - off] : 0;
    __syncthreads();
    tmp[tid] += t;
    __syncthreads();
  }
  if (i < N_ENT) exc[i] = tmp[tid] - v;
  if (tid == 1023) bsum[blockIdx.x] = tmp[1023];
}

// Phase 2: one wave scans the 49 block sums -> exclusive offsets (+ total at [NBLK])
__global__ void scan2_kernel(const int* __restrict__ bsum, int* __restrict__ boff) {
  int t = threadIdx.x;  // 64 threads
  int v = (t < NBLK) ? bsum[t] : 0;
  int incl = v;
#pragma unroll
  for (int off = 1; off < 64; off <<= 1) {
    int u = __shfl_up(incl, off);
    if (t >= off) incl += u;
  }
  if (t < NBLK) boff[t] = incl - v;
  if (t == NBLK - 1) boff[NBLK] = incl;
}

// Phase 3: add block offsets -> rowptr
__global__ __launch_bounds__(1024) void scan3_kernel(const int* __restrict__ exc,
                                                     const int* __restrict__ boff,
                                                     int* __restrict__ rowptr) {
  int i = blockIdx.x * 1024 + threadIdx.x;
  if (i < N_ENT) rowptr[i] = exc[i] + boff[i >> 10];
  if (i == N_ENT) rowptr[N_ENT] = boff[NBLK];
}

// scatter: csr_dst[p] = dst[e]; pos[e] = p
__global__ void scatter_kernel(const int* __restrict__ src, const int* __restrict__ dst,
                               int* __restrict__ cursor, int* __restrict__ csr_dst,
                               int* __restrict__ pos) {
  int e = blockIdx.x * blockDim.x + threadIdx.x;
  if (e >= N_EDGE) return;
  int p = atomicAdd(&cursor[src[e]], 1);
  csr_dst[p] = dst[e];
  pos[e] = p;
}

// ================= LayerNorm: one wave per node =================
__global__ void ln_kernel(const float* __restrict__ x, const float* __restrict__ g,
                          const float* __restrict__ b, float* __restrict__ h) {
  int wid = (blockIdx.x * blockDim.x + threadIdx.x) >> 6;
  int lane = threadIdx.x & 63;
  if (wid >= N_ENT) return;
  float v = x[wid * 64 + lane];
  float s = v;
#pragma unroll
  for (int off = 32; off; off >>= 1) s += __shfl_xor(s, off);
  float mu = s * (1.0f / 64.0f);
  float d = v - mu;
  float s2 = d * d;
#pragma unroll
  for (int off = 32; off; off >>= 1) s2 += __shfl_xor(s2, off);
  float rs = rsqrtf(s2 * (1.0f / 64.0f) + LN_EPS);
  h[wid * 64 + lane] = d * rs * g[lane] + b[lane];
}

// ================= node scores: W column in VGPRs, x row via scalar loads =================
__global__ __launch_bounds__(256) void scores_w_kernel(
    const float* __restrict__ x, const float* __restrict__ W,
    const float* __restrict__ att, float* __restrict__ s_out, int M) {
  int lane = threadIdx.x & 63;
  float w0[64], w1[64];
#pragma unroll
  for (int k = 0; k < 64; ++k) {
    w0[k] = W[k * 128 + lane];
    w1[k] = W[k * 128 + lane + 64];
  }
  float a0v = att[lane], a1v = att[lane + 64];
  int gw = (blockIdx.x * 256 + threadIdx.x) >> 6;
  int nw = (gridDim.x * 256) >> 6;
  for (int n = gw; n < M; n += nw) {
    int nu = __builtin_amdgcn_readfirstlane(n);
    const float* xr = x + nu * 64;
    float p0 = 0.f, p1 = 0.f, p2 = 0.f, p3 = 0.f;
#pragma unroll
    for (int k = 0; k < 32; ++k) {
      float xa = xr[k], xb = xr[k + 32];
      p0 += xa * w0[k];
      p1 += xb * w0[k + 32];
      p2 += xa * w1[k];
      p3 += xb * w1[k + 32];
    }
    float t0 = tanhf(p0 + p1) * a0v;
    float t1 = tanhf(p2 + p3) * a1v;
#pragma unroll
    for (int off = 32; off; off >>= 1) {
      t0 += __shfl_xor(t0, off);
      t1 += __shfl_xor(t1, off);
    }
    if (lane == 0) ((float2*)s_out)[nu] = make_float2(t0, t1);
  }
}

// ================= fused edge pass: score -> leaky_relu -> exp -> csr_w + z =================
__global__ void edge_kernel(const int* __restrict__ src, const int* __restrict__ dst,
                            const int* __restrict__ et, const float* __restrict__ s_h,
                            const float* __restrict__ s_t, const float* __restrict__ s_r,
                            const int* __restrict__ pos, float* __restrict__ csr_w,
                            float* __restrict__ z) {
  int e = blockIdx.x * blockDim.x + threadIdx.x;
  if (e >= N_EDGE) return;
  int s = src[e], d = dst[e], r = et[e];
  float2 a = ((const float2*)s_h)[s];
  float2 b = ((const float2*)s_t)[d];
  float2 c = ((const float2*)s_r)[r];
  float sc0 = a.x + b.x + c.x;
  float sc1 = a.y + b.y + c.y;
  sc0 = (sc0 >= 0.f) ? sc0 : 0.01f * sc0;
  sc1 = (sc1 >= 0.f) ? sc1 : 0.01f * sc1;
  float w0 = expf(sc0), w1 = expf(sc1);
  ((float2*)csr_w)[pos[e]] = make_float2(w0, w1);
  atomicAdd(&z[s * 2 + 0], w0);
  atomicAdd(&z[s * 2 + 1], w1);
}

// ================= CSR SpMM: wave per node; 4 edge slots x 8 dims/lane =================
// IN_H=1: gather f32 h rows (64-dim, head-broadcast). IN_H=0: gather bf16 Z rows (128-dim).
// OUT_F32=1: write f32 (final iter, feeds out_kernel). OUT_F32=0: write packed bf16.
template <int IN_H, int OUT_F32>
__global__ __launch_bounds__(256) void spmm_kernel(
    const int* __restrict__ rowptr, const int* __restrict__ csr_dst,
    const float* __restrict__ csr_w, const float* __restrict__ z,
    const float* __restrict__ h, const void* __restrict__ Zin_,
    void* __restrict__ Zout_) {
  const float* Zin_f = (const float*)Zin_;
  const unsigned short* Zin_b = (const unsigned short*)Zin_;
  int lane = threadIdx.x & 63;
  int slot = lane >> 4;        // 4 edge slots per wave
  int l16 = lane & 15;         // dims 8*l16 .. 8*l16+7
  int hh = l16 >> 3;           // head
  int hoff = 8 * (l16 & 7);    // offset within 64-dim head row
  int gw = (blockIdx.x * 256 + threadIdx.x) >> 6;
  int nw = (gridDim.x * 256) >> 6;
  for (int n = gw; n < N_ENT; n += nw) {
    int p0 = rowptr[n], p1 = rowptr[n + 1];
    float acc[8];
#pragma unroll
    for (int j = 0; j < 8; ++j) acc[j] = 0.f;
    for (int p = p0 + slot; p < p1; p += 4) {
      int d = csr_dst[p];
      float2 w2 = ((const float2*)csr_w)[p];
      float a = hh ? w2.y : w2.x;
      float f[8];
      if (IN_H) {
        const float* zp = Zin_f + d * 64 + hoff;
        float4 z0 = *(const float4*)zp;
        float4 z1 = *(const float4*)(zp + 4);
        f[0] = z0.x; f[1] = z0.y; f[2] = z0.z; f[3] = z0.w;
        f[4] = z1.x; f[5] = z1.y; f[6] = z1.z; f[7] = z1.w;
      } else {
        uint4 q = *(const uint4*)(Zin_b + d * 128 + 8 * l16);
        f[0] = __uint_as_float(q.x << 16); f[1] = __uint_as_float(q.x & 0xFFFF0000u);
        f[2] = __uint_as_float(q.y << 16); f[3] = __uint_as_float(q.y & 0xFFFF0000u);
        f[4] = __uint_as_float(q.z << 16); f[5] = __uint_as_float(q.z & 0xFFFF0000u);
        f[6] = __uint_as_float(q.w << 16); f[7] = __uint_as_float(q.w & 0xFFFF0000u);
      }
#pragma unroll
      for (int j = 0; j < 8; ++j) acc[j] += a * f[j];
    }
#pragma unroll
    for (int j = 0; j < 8; ++j) {
      acc[j] += __shfl_xor(acc[j], 16);
      acc[j] += __shfl_xor(acc[j], 32);
    }
    if (slot == 0) {
      float c = (p1 > p0) ? (1.0f - ALPHA) / z[n * 2 + hh] : 0.f;
      const float* hp = h + n * 64 + hoff;
      float o[8];
#pragma unroll
      for (int j = 0; j < 8; ++j) o[j] = acc[j] * c + ALPHA * hp[j];
      if (OUT_F32) {
        float* op = (float*)Zout_ + n * 128 + 8 * l16;
        *(float4*)op = make_float4(o[0], o[1], o[2], o[3]);
        *(float4*)(op + 4) = make_float4(o[4], o[5], o[6], o[7]);
      } else {
        unsigned short* ob = (unsigned short*)Zout_ + n * 128 + 8 * l16;
        uint4 qo;
        qo.x = bf16_rne(o[0]) | (bf16_rne(o[1]) << 16);
        qo.y = bf16_rne(o[2]) | (bf16_rne(o[3]) << 16);
        qo.z = bf16_rne(o[4]) | (bf16_rne(o[5]) << 16);
        qo.w = bf16_rne(o[6]) | (bf16_rne(o[7]) << 16);
        *(uint4*)ob = qo;
      }
    }
  }
}

// ================= output: lane = column j; W_o column in 128 VGPRs; Z row via s_load =================
__global__ __launch_bounds__(256) void out_kernel(
    const float* __restrict__ Z, const float* __restrict__ Wo,
    const float* __restrict__ x, float* __restrict__ out) {
  int lane = threadIdx.x & 63;
  float wo[128];
#pragma unroll
  for (int c = 0; c < 128; ++c) wo[c] = Wo[c * 64 + lane];
  int gw = (blockIdx.x * 256 + threadIdx.x) >> 6;
  int nw = (gridDim.x * 256) >> 6;
  for (int n = gw; n < N_ENT; n += nw) {
    int nu = __builtin_amdgcn_readfirstlane(n);
    const float* zr = Z + nu * 128;
    float a0 = 0.f, a1 = 0.f, a2 = 0.f, a3 = 0.f;
#pragma unroll
    for (int c = 0; c < 32; ++c) {
      a0 += zr[c] * wo[c];
      a1 += zr[c + 32] * wo[c + 32];
      a2 += zr[c + 64] * wo[c + 64];
      a3 += zr[c + 96] * wo[c + 96];
    }
    out[nu * 64 + lane] = (a0 + a1) + (a2 + a3) + x[nu * 64 + lane];
  }
}

extern "C" void kernel_launch(void* const* d_in, const int* in_sizes, int n_in,
                              void* d_out, int out_size, void* d_ws, size_t ws_size,
                              hipStream_t stream) {
  const float* ent0 = (const float*)d_in[0];
  const float* rel  = (const float*)d_in[1];
  const int* eidx   = (const int*)d_in[2];
  const int* src    = eidx;
  const int* dst    = eidx + N_EDGE;
  const int* et     = (const int*)d_in[3];
  const float* gam  = (const float*)d_in[4];
  const float* bet  = (const float*)d_in[5];
  const float* W_h  = (const float*)d_in[6];
  const float* W_t  = (const float*)d_in[7];
  const float* W_r  = (const float*)d_in[8];
  const float* att_h = (const float*)d_in[9];
  const float* att_t = (const float*)d_in[10];
  const float* att_r = (const float*)d_in[11];
  const float* W_o  = (const float*)d_in[12];
  float* outp = (float*)d_out;

  char* w = (char*)d_ws;
  auto alloc = [&](size_t bytes) {
    char* p = w;
    w += (bytes + 255) & ~(size_t)255;
    return p;
  };
  float* ent1   = (float*)alloc((size_t)N_ENT * 64 * 4);
  float* h      = (float*)alloc((size_t)N_ENT * 64 * 4);
  float* s_h    = (float*)alloc((size_t)N_ENT * 2 * 4);
  float* s_t    = (float*)alloc((size_t)N_ENT * 2 * 4);
  float* s_r    = (float*)alloc((size_t)N_REL * 2 * 4);
  float* z      = (float*)alloc((size_t)N_ENT * 2 * 4);
  float* csr_w  = (float*)alloc((size_t)N_EDGE * 2 * 4);
  unsigned short* Zb0 = (unsigned short*)alloc((size_t)N_ENT * 128 * 2);
  unsigned short* Zb1 = (unsigned short*)alloc((size_t)N_ENT * 128 * 2);
  float* Zf     = (float*)alloc((size_t)N_ENT * 128 * 4);
  int* deg      = (int*)alloc((size_t)N_ENT * 4);
  int* exc      = (int*)alloc((size_t)N_ENT * 4);
  int* bsum     = (int*)alloc((size_t)NBLK * 4);
  int* boff     = (int*)alloc((size_t)(NBLK + 1) * 4);
  int* rowptr   = (int*)alloc((size_t)(N_ENT + 1) * 4);
  int* cursor   = (int*)alloc((size_t)N_ENT * 4);
  int* csr_dst  = (int*)alloc((size_t)N_EDGE * 4);
  int* pos      = (int*)alloc((size_t)N_EDGE * 4);

  const int EB = (N_EDGE + 255) / 256;

  // ---- CSR build (multi-block scan) ----
  hipMemsetAsync(deg, 0, (size_t)N_ENT * 4, stream);
  deg_kernel<<<EB, 256, 0, stream>>>(src, deg);
  scan1_kernel<<<NBLK, 1024, 0, stream>>>(deg, exc, bsum);
  scan2_kernel<<<1, 64, 0, stream>>>(bsum, boff);
  scan3_kernel<<<NBLK, 1024, 0, stream>>>(exc, boff, rowptr);
  hipMemcpyAsync(cursor, rowptr, (size_t)N_ENT * 4, hipMemcpyDeviceToDevice, stream);
  scatter_kernel<<<EB, 256, 0, stream>>>(src, dst, cursor, csr_dst, pos);

  for (int l = 0; l < 2; ++l) {
    const float* x = (l == 0) ? ent0 : ent1;
    float* y = (l == 0) ? ent1 : outp;

    ln_kernel<<<(N_ENT + 3) / 4, 256, 0, stream>>>(x, gam + l * 64, bet + l * 64, h);
    scores_w_kernel<<<1024, 256, 0, stream>>>(h, W_h + l * 8192, att_h + l * 128, s_h, N_ENT);
    scores_w_kernel<<<1024, 256, 0, stream>>>(h, W_t + l * 8192, att_t + l * 128, s_t, N_ENT);
    scores_w_kernel<<<8, 256, 0, stream>>>(rel, W_r + l * 8192, att_r + l * 128, s_r, N_REL);

    hipMemsetAsync(z, 0, (size_t)N_ENT * 2 * 4, stream);
    edge_kernel<<<EB, 256, 0, stream>>>(src, dst, et, s_h, s_t, s_r, pos, csr_w, z);

    // ---- PPR power iteration: h(f32) -> bf16 -> bf16 -> f32 ----
    spmm_kernel<1, 0><<<2048, 256, 0, stream>>>(rowptr, csr_dst, csr_w, z, h, h, Zb0);
    spmm_kernel<0, 0><<<2048, 256, 0, stream>>>(rowptr, csr_dst, csr_w, z, h, Zb0, Zb1);
    spmm_kernel<0, 1><<<2048, 256, 0, stream>>>(rowptr, csr_dst, csr_w, z, h, Zb1, Zf);

    out_kernel<<<512, 256, 0, stream>>>(Zf, W_o + l * 8192, x, y);
  }
}